// Round 2
// 452.298 us; speedup vs baseline: 1.0607x; 1.0607x over previous
//
#include <hip/hip_runtime.h>

// ---------------------------------------------------------------------------
// CrossLevelAttention on MI355X — round 3 (resubmit; round-1 bench was an
// infra failure, no kernel verdict).
//   conv1x1 GEMMs (bf16 MFMA, fp32 out)  -> pyramid dwconv (fp32 in, bf16 out)
//   -> MFMA-based scores+sq-norms (bf16 in, fp32 atomics)
//   -> softmax+projection-fold (CT bf16) -> output GEMM (v read as bf16).
// Changes vs round 2: CPB=1 grids (4x blocks), low-VGPR wave shapes,
// conflict-free LDS staging map, bf16 pyramided buffers, MFMA scores.
// ---------------------------------------------------------------------------

#define NPIX 65536  // 256*256 per batch image

using bf16x8 = __attribute__((ext_vector_type(8))) short;
using f32x4  = __attribute__((ext_vector_type(4))) float;

__device__ __forceinline__ unsigned short f2bf(float f) {
    unsigned u = __builtin_bit_cast(unsigned, f);
    u = u + 0x7FFF + ((u >> 16) & 1);   // RNE
    return (unsigned short)(u >> 16);
}
__device__ __forceinline__ float bf2f(unsigned short u) {
    return __builtin_bit_cast(float, (unsigned)u << 16);
}

// ---------------- zero small accumulator region ----------------
__global__ void zero_k(float* __restrict__ p, int n) {
    int i = blockIdx.x * 256 + threadIdx.x;
    if (i < n) p[i] = 0.f;
}

// ---------------- cast 1x1 weights to bf16 (keep [o][k] layout) -------------
__global__ void cast_w_k(const float* __restrict__ w_kv,
                         const float* __restrict__ w_qh,
                         const float* __restrict__ w_ql,
                         unsigned short* __restrict__ wkv_b,
                         unsigned short* __restrict__ wqh_b,
                         unsigned short* __restrict__ wql_b) {
    int idx = blockIdx.x * 256 + threadIdx.x;
    if (idx < 32768) wkv_b[idx] = f2bf(w_kv[idx]);
    else if (idx < 32768 + 4096) wqh_b[idx - 32768] = f2bf(w_qh[idx - 32768]);
    else if (idx < 32768 + 4096 + 1024) wql_b[idx - 36864] = f2bf(w_ql[idx - 36864]);
}

// ---------------- generic MFMA GEMM over pixel dimension --------------------
// out[b][o][n] = sum_k A[o][k] * src[b][k][n],  O = MW*MSPLIT*16, K = KT*32.
// One 64-pixel chunk per block; B staged transposed+bf16-packed in LDS.
// Staging map (sn,kp0)=(t>>2,t&3): LDS write banks = 4*(sn&7)+kp0 -> 32
// distinct banks, 2 lanes each (conflict-free).
template <int MW, int MSPLIT, int KT, bool SPLIT, bool SRCBF>
__global__ __launch_bounds__(256) void gemm_mfma_k(
    const void* __restrict__ srcv, const unsigned short* __restrict__ A,
    float* __restrict__ out, float* __restrict__ out2,
    long srcBStride, long aBStride, long outBStride, long out2BStride) {
    constexpr int K  = KT * 32;
    constexpr int RW = K / 2 + 4;   // LDS row pitch in 32-bit words (16B-aligned)
    constexpr int NW = MSPLIT;      // N tiles per wave (chunk is always 64 px)

    __shared__ unsigned Blds[64 * RW];

    const int t    = threadIdx.x;
    const int wave = t >> 6;
    const int lane = t & 63;
    const int r    = lane & 15;
    const int q    = lane >> 4;

    const int chunk = blockIdx.x;
    const int b     = chunk >> 10;          // 1024 chunks per batch
    const int n0    = (chunk & 1023) * 64;
    const int m0    = (wave % MSPLIT) * MW * 16;
    const int nb    = (wave / MSPLIT) * NW * 16;

    // A fragments: [o][k] bf16, k-contiguous -> direct 16B loads
    bf16x8 af[MW][KT];
    {
        const unsigned short* Ab = A + (size_t)b * aBStride;
#pragma unroll
        for (int mw = 0; mw < MW; ++mw)
#pragma unroll
            for (int kt = 0; kt < KT; ++kt)
                af[mw][kt] = *(const bf16x8*)(Ab + (size_t)(m0 + mw * 16 + r) * K + kt * 32 + q * 8);
    }

    // stage K x 64 -> LDS bf16 transposed [n][k/2 packed]
    {
        const int sn = t >> 2, kp0 = t & 3;
        if constexpr (SRCBF) {
            const unsigned short* sp = (const unsigned short*)srcv + (size_t)b * srcBStride + n0 + sn;
#pragma unroll
            for (int it = 0; it < K / 8; ++it) {
                const int kp = it * 4 + kp0;
                const unsigned v0 = sp[(size_t)(2 * kp) * NPIX];
                const unsigned v1 = sp[(size_t)(2 * kp + 1) * NPIX];
                Blds[sn * RW + kp] = v0 | (v1 << 16);
            }
        } else {
            const float* sp = (const float*)srcv + (size_t)b * srcBStride + n0 + sn;
#pragma unroll
            for (int it = 0; it < K / 8; ++it) {
                const int kp = it * 4 + kp0;
                const float v0 = sp[(size_t)(2 * kp) * NPIX];
                const float v1 = sp[(size_t)(2 * kp + 1) * NPIX];
                Blds[sn * RW + kp] = (unsigned)f2bf(v0) | ((unsigned)f2bf(v1) << 16);
            }
        }
    }
    __syncthreads();

    f32x4 acc[MW][NW];
#pragma unroll
    for (int mw = 0; mw < MW; ++mw)
#pragma unroll
        for (int nw = 0; nw < NW; ++nw) acc[mw][nw] = (f32x4){0.f, 0.f, 0.f, 0.f};

#pragma unroll
    for (int kt = 0; kt < KT; ++kt) {
        bf16x8 bf[NW];
#pragma unroll
        for (int nw = 0; nw < NW; ++nw) {
            const int n = nb + nw * 16 + r;
            bf[nw] = *(const bf16x8*)(&Blds[n * RW + kt * 16 + q * 4]);
        }
#pragma unroll
        for (int mw = 0; mw < MW; ++mw)
#pragma unroll
            for (int nw = 0; nw < NW; ++nw)
                acc[mw][nw] = __builtin_amdgcn_mfma_f32_16x16x32_bf16(
                    af[mw][kt], bf[nw], acc[mw][nw], 0, 0, 0);
    }

    // store: C/D layout col=lane&15 (pixel), row=(lane>>4)*4+reg (channel)
#pragma unroll
    for (int mw = 0; mw < MW; ++mw) {
        const int obase = m0 + mw * 16 + q * 4;
#pragma unroll
        for (int nw = 0; nw < NW; ++nw) {
            const int n = n0 + nb + nw * 16 + r;
#pragma unroll
            for (int rr = 0; rr < 4; ++rr) {
                const int o = obase + rr;
                float* dst;
                if (SPLIT && o >= 128)
                    dst = out2 + (size_t)b * out2BStride + (size_t)(o - 128) * NPIX + n;
                else
                    dst = out + (size_t)b * outBStride + (size_t)o * NPIX + n;
                *dst = acc[mw][nw][rr];
            }
        }
    }
}

// ---------------- pyramid depthwise conv (reflect pad, dilation=group) ------
// fp32 raw in, bf16 out. One (b,c,y) row per block; 3 input rows staged in LDS.
__device__ __forceinline__ int refl(int p) {
    return (p < 0) ? -p : ((p > 255) ? 510 - p : p);
}

__global__ __launch_bounds__(256) void pyramid_k(const float* __restrict__ in,
                                                 unsigned short* __restrict__ out, int C,
                                                 const float* __restrict__ w1,
                                                 const float* __restrict__ w2,
                                                 const float* __restrict__ w3) {
    const int t = threadIdx.x;
    const int bi = blockIdx.x;
    const int y = bi & 255;
    const int bc = bi >> 8;
    const int G = C >> 2;
    const int c = bc % C;
    const int g = (c >= 3 * G) ? 3 : (c >= 2 * G) ? 2 : (c >= G) ? 1 : 0;

    const float* src = in + (size_t)bc * NPIX;
    const size_t oidx = (size_t)bc * NPIX + y * 256 + t;

    if (g == 0) {
        out[oidx] = f2bf(src[y * 256 + t]);
        return;
    }

    __shared__ float rows[3][256];
    const int y0 = refl(y - g), y2 = refl(y + g);
    for (int i = t; i < 384; i += 256) {
        const int rr  = i >> 7;           // 0..2
        const int off = (i & 127) * 2;
        const int yy  = (rr == 0) ? y0 : (rr == 1) ? y : y2;
        const float2 v = *(const float2*)(src + yy * 256 + off);
        rows[rr][off] = v.x;
        rows[rr][off + 1] = v.y;
    }
    __syncthreads();

    const float* wp = (g == 1 ? w1 : (g == 2 ? w2 : w3)) + (c - g * G) * 9;
    const int xm = refl(t - g), xp = refl(t + g);
    float s = 0.f;
#pragma unroll
    for (int ky = 0; ky < 3; ++ky) {
        s = fmaf(wp[ky * 3 + 0], rows[ky][xm], s);
        s = fmaf(wp[ky * 3 + 1], rows[ky][t], s);
        s = fmaf(wp[ky * 3 + 2], rows[ky][xp], s);
    }
    out[oidx] = f2bf(s);
}

// ---------------- MFMA scores + squared-norm reductions ---------------------
// S[c][d] = sum_n q[c,n]*k[d,n] per (b,hd): K=65536 reduction GEMM.
// A lane(r,q) holds q-row c=r (r<12, else dummy), 8 px; B holds k-row d=r.
// D layout: row=c=(lane>>4)*4+reg, col=d=lane&15  (verified convention).
// Sbuf layout (floats): [0,1536) S[b][hd][c][d]; [1536,1664) kk; [1664,1760) qq.
__global__ __launch_bounds__(256) void scores_k(const unsigned short* __restrict__ qhp,
                                                const unsigned short* __restrict__ qlp,
                                                const unsigned short* __restrict__ kvp,
                                                float* __restrict__ Sbuf) {
    const int t = threadIdx.x;
    const int wave = t >> 6, lane = t & 63;
    const int r = lane & 15, q = lane >> 4;
    const int slice = blockIdx.x;   // 64 slices of 1024 px
    const int hd = blockIdx.y;
    const int b = blockIdx.z;

    const unsigned short* qrow;
    if (r < 8)       qrow = qhp + (size_t)(b * 32 + hd * 8 + r) * NPIX;
    else if (r < 12) qrow = qlp + (size_t)(b * 16 + hd * 4 + (r - 8)) * NPIX;
    else             qrow = qhp + (size_t)(b * 32 + hd * 8) * NPIX;  // dummy (rows 12..15 unused)
    const unsigned short* krow = kvp + (size_t)(b * 128 + hd * 16 + r) * NPIX;

    const int base = slice * 1024 + wave * 256;  // wave covers 256 px = 8 chunks of 32
    f32x4 acc = (f32x4){0.f, 0.f, 0.f, 0.f};
    float qq = 0.f, kk = 0.f;
#pragma unroll
    for (int c8 = 0; c8 < 8; ++c8) {
        const int n = base + c8 * 32 + q * 8;
        const bf16x8 a  = *(const bf16x8*)(qrow + n);
        const bf16x8 bb = *(const bf16x8*)(krow + n);
        acc = __builtin_amdgcn_mfma_f32_16x16x32_bf16(a, bb, acc, 0, 0, 0);
#pragma unroll
        for (int j = 0; j < 8; ++j) {
            const float av = bf2f((unsigned short)a[j]);
            const float bv = bf2f((unsigned short)bb[j]);
            qq = fmaf(av, av, qq);
            kk = fmaf(bv, bv, kk);
        }
    }
    // reduce qq/kk over the 4 q-groups (lanes differing in bits 4,5)
    qq += __shfl_xor(qq, 16); qq += __shfl_xor(qq, 32);
    kk += __shfl_xor(kk, 16); kk += __shfl_xor(kk, 32);

    __shared__ float Sred[4][16][16];
    __shared__ float qred[4][16];
    __shared__ float kred[4][16];
#pragma unroll
    for (int rr = 0; rr < 4; ++rr) Sred[wave][q * 4 + rr][r] = acc[rr];
    if (q == 0) { qred[wave][r] = qq; kred[wave][r] = kk; }
    __syncthreads();

    if (t < 192) {
        const int c = t >> 4, d = t & 15;
        const float s = Sred[0][c][d] + Sred[1][c][d] + Sred[2][c][d] + Sred[3][c][d];
        if (c < 12) atomicAdd(&Sbuf[((b * 4 + hd) * 12 + c) * 16 + d], s);
    } else if (t < 208) {
        const int d = t - 192;
        const float s = kred[0][d] + kred[1][d] + kred[2][d] + kred[3][d];
        atomicAdd(&Sbuf[1536 + (b * 4 + hd) * 16 + d], s);
    } else if (t < 220) {
        const int c = t - 208;
        const float s = qred[0][c] + qred[1][c] + qred[2][c] + qred[3][c];
        atomicAdd(&Sbuf[1664 + (b * 4 + hd) * 12 + c], s);
    }
}

// ---------------- softmax + fold output projections into CT (bf16) ---------
// CT[b][r(192)][j=hd*16+d (64)]: rows 0..127 -> out_h (w_ph), 128..191 -> out_l.
__global__ __launch_bounds__(256) void finalize_k(const float* __restrict__ Sbuf,
                                                  const float* __restrict__ w_ph,
                                                  const float* __restrict__ w_pl,
                                                  const float* __restrict__ temp,
                                                  unsigned short* __restrict__ CT) {
    __shared__ float As[192];
    const int t = threadIdx.x;
    const int hd = blockIdx.x;
    const int b = blockIdx.y;

    if (t < 192) {
        const int c = t >> 4, d = t & 15;
        const float kss = Sbuf[1536 + (b * 4 + hd) * 16 + d];
        const float qss = Sbuf[1664 + (b * 4 + hd) * 12 + c];
        const float invk = 1.f / fmaxf(sqrtf(kss), 1e-12f);
        const float invq = 1.f / fmaxf(sqrtf(qss), 1e-12f);
        float s = Sbuf[((b * 4 + hd) * 12 + c) * 16 + d] * invq * invk * temp[hd];
        float m = s;
        for (int mask = 8; mask >= 1; mask >>= 1) m = fmaxf(m, __shfl_xor(m, mask, 16));
        const float e = expf(s - m);
        float sum = e;
        for (int mask = 8; mask >= 1; mask >>= 1) sum += __shfl_xor(sum, mask, 16);
        As[c * 16 + d] = e / sum;
    }
    __syncthreads();

    unsigned short* CTb = CT + (size_t)b * 192 * 64;
    for (int idx = t; idx < 3072; idx += 256) {
        const int d = idx & 15, rr = idx >> 4;
        float s = 0.f;
        if (rr < 128) {
#pragma unroll
            for (int c = 0; c < 8; ++c)
                s = fmaf(w_ph[rr * 32 + hd * 8 + c], As[c * 16 + d], s);
        } else {
            const int r2 = rr - 128;
#pragma unroll
            for (int c = 0; c < 4; ++c)
                s = fmaf(w_pl[r2 * 16 + hd * 4 + c], As[(8 + c) * 16 + d], s);
        }
        CTb[(size_t)rr * 64 + hd * 16 + d] = f2bf(s);
    }
}

// ---------------------------------------------------------------------------
extern "C" void kernel_launch(void* const* d_in, const int* in_sizes, int n_in,
                              void* d_out, int out_size, void* d_ws, size_t ws_size,
                              hipStream_t stream) {
    const float* x      = (const float*)d_in[0];
    const float* x_h    = (const float*)d_in[1];
    const float* x_l    = (const float*)d_in[2];
    const float* w_kv   = (const float*)d_in[3];
    const float* kv_dw1 = (const float*)d_in[4];
    const float* kv_dw2 = (const float*)d_in[5];
    const float* kv_dw3 = (const float*)d_in[6];
    const float* w_qh   = (const float*)d_in[7];
    const float* qh_dw1 = (const float*)d_in[8];
    const float* qh_dw2 = (const float*)d_in[9];
    const float* qh_dw3 = (const float*)d_in[10];
    const float* w_ql   = (const float*)d_in[11];
    const float* ql_dw1 = (const float*)d_in[12];
    const float* ql_dw2 = (const float*)d_in[13];
    const float* ql_dw3 = (const float*)d_in[14];
    const float* w_ph   = (const float*)d_in[15];
    const float* w_pl   = (const float*)d_in[16];
    const float* temp   = (const float*)d_in[17];
    float* out = (float*)d_out;

    char* ws = (char*)d_ws;
    float*          Sbuf  = (float*)(ws + 0);                // 7040 B
    unsigned short* wkv_b = (unsigned short*)(ws + 8192);    // 65536 B
    unsigned short* wqh_b = (unsigned short*)(ws + 73728);   // 8192 B
    unsigned short* wql_b = (unsigned short*)(ws + 81920);   // 2048 B
    unsigned short* CT    = (unsigned short*)(ws + 90112);   // 49152 B
    float*          kvraw = (float*)(ws + 262144);           // 67108864 B (fp32)
    float*          qhraw = (float*)(ws + 67371008);         // 16777216 B
    float*          qlraw = (float*)(ws + 84148224);         //  8388608 B
    unsigned short* kvpyr = (unsigned short*)(ws + 92536832);   // 33554432 B (bf16)
    unsigned short* qhpyr = (unsigned short*)(ws + 126091264);  //  8388608 B
    unsigned short* qlpyr = (unsigned short*)(ws + 134479872);  //  4194304 B

    zero_k<<<7, 256, 0, stream>>>(Sbuf, 1760);
    cast_w_k<<<148, 256, 0, stream>>>(w_kv, w_qh, w_ql, wkv_b, wqh_b, wql_b);

    // kv: O=128 (MW=2,MS=4), K=256 (KT=8)
    gemm_mfma_k<2, 4, 8, false, false><<<2048, 256, 0, stream>>>(
        x, wkv_b, kvraw, nullptr, 256L * NPIX, 0L, 128L * NPIX, 0L);
    // qh: O=32 (MW=2,MS=1), K=128 (KT=4)
    gemm_mfma_k<2, 1, 4, false, false><<<2048, 256, 0, stream>>>(
        x_h, wqh_b, qhraw, nullptr, 128L * NPIX, 0L, 32L * NPIX, 0L);
    // ql: O=16 (MW=1,MS=1), K=64 (KT=2)
    gemm_mfma_k<1, 1, 2, false, false><<<2048, 256, 0, stream>>>(
        x_l, wql_b, qlraw, nullptr, 64L * NPIX, 0L, 16L * NPIX, 0L);

    pyramid_k<<<65536, 256, 0, stream>>>(kvraw, kvpyr, 128, kv_dw1, kv_dw2, kv_dw3);
    pyramid_k<<<16384, 256, 0, stream>>>(qhraw, qhpyr, 32, qh_dw1, qh_dw2, qh_dw3);
    pyramid_k<<<8192, 256, 0, stream>>>(qlraw, qlpyr, 16, ql_dw1, ql_dw2, ql_dw3);

    scores_k<<<dim3(64, 4, 2), 256, 0, stream>>>(qhpyr, qlpyr, kvpyr, Sbuf);
    finalize_k<<<dim3(4, 2), 256, 0, stream>>>(Sbuf, w_ph, w_pl, temp, CT);

    // output GEMM: O=192 (MW=3,MS=4), K=64 (KT=2); A = CT per batch;
    // B = v = kvpyr channels 64..127 (bf16); rows >=128 go to out_l.
    gemm_mfma_k<3, 4, 2, true, true><<<2048, 256, 0, stream>>>(
        (const void*)(kvpyr + 64L * NPIX), CT, out, out + 2L * 128 * NPIX,
        128L * NPIX, 192L * 64, 128L * NPIX, 64L * NPIX);
}

// Round 3
// 399.956 us; speedup vs baseline: 1.1995x; 1.1309x over previous
//
#include <hip/hip_runtime.h>

// ---------------------------------------------------------------------------
// CrossLevelAttention on MI355X — round 4.
// GEMM template rebuilt: float4/ushort4 coalesced staging, XOR-swizzled LDS
// (conflict-min ds_read_b128), CPB=4 pipelined chunks with double-buffered LDS
// + counted vmcnt + single raw barrier per chunk (stores never drained).
// Pyramid merged to one launch with 32-row LDS tiles. scores -> slice
// partials (no atomics / no zero kernel).
// ---------------------------------------------------------------------------

#define NPIX 65536  // 256*256 per batch image

using bf16x8 = __attribute__((ext_vector_type(8))) short;
using f32x4  = __attribute__((ext_vector_type(4))) float;
using f4     = __attribute__((ext_vector_type(4))) float;
using us4    = __attribute__((ext_vector_type(4))) unsigned short;

__device__ __forceinline__ unsigned short f2bf(float f) {
    unsigned u = __builtin_bit_cast(unsigned, f);
    u = u + 0x7FFF + ((u >> 16) & 1);   // RNE
    return (unsigned short)(u >> 16);
}
__device__ __forceinline__ float bf2f(unsigned short u) {
    return __builtin_bit_cast(float, (unsigned)u << 16);
}

// ---------------- cast 1x1 weights to bf16 (keep [o][k] layout) -------------
__global__ void cast_w_k(const float* __restrict__ w_kv,
                         const float* __restrict__ w_qh,
                         const float* __restrict__ w_ql,
                         unsigned short* __restrict__ wkv_b,
                         unsigned short* __restrict__ wqh_b,
                         unsigned short* __restrict__ wql_b) {
    int idx = blockIdx.x * 256 + threadIdx.x;
    if (idx < 32768) wkv_b[idx] = f2bf(w_kv[idx]);
    else if (idx < 32768 + 4096) wqh_b[idx - 32768] = f2bf(w_qh[idx - 32768]);
    else if (idx < 32768 + 4096 + 1024) wql_b[idx - 36864] = f2bf(w_ql[idx - 36864]);
}

// ---------------- generic MFMA GEMM over pixel dimension --------------------
// out[b][o][n] = sum_k A[o][k] * src[b][k][n],  O = MW*MSPLIT*16, K = KT*32.
// CPB 64-px chunks per block; pipelined: loads(c+1) in flight under compute(c);
// double-buffered LDS; counted vmcnt so stores are never drained in the loop.
// LDS word layout: word(n,kp) = n*(K/2) + (((kp>>2) ^ ((n>>1)&7))<<2) + (kp&3)
// where kp = packed k-pair index. Reads: uniform 8/bank (min for b128).
template <int MW, int MSPLIT, int KT, int CPB, bool SPLIT, bool SRCBF>
__global__ __launch_bounds__(256, 2) void gemm_mfma_k(
    const void* __restrict__ srcv, const unsigned short* __restrict__ A,
    float* __restrict__ out, float* __restrict__ out2,
    long srcBStride, long aBStride, long outBStride, long out2BStride) {
    constexpr int K     = KT * 32;
    constexpr int KW    = K / 2;        // 32-bit words per LDS row
    constexpr int NW    = MSPLIT;       // N tiles per wave (chunk is 64 px)
    constexpr int ITERS = K / 32;       // staging iterations
    constexpr int SCNT  = MW * NW * 4;  // global stores per chunk per thread

    __shared__ __align__(16) unsigned Blds[2][64 * KW];

    const int t    = threadIdx.x;
    const int wave = t >> 6;
    const int lane = t & 63;
    const int r    = lane & 15;
    const int q    = lane >> 4;
    const int h    = t >> 4;            // 0..15: staging row-pair sub-index
    const int m4   = (t & 15) * 4;      // staging pixel quad

    const int chunk0 = blockIdx.x * CPB;
    const int b      = chunk0 >> 10;    // 1024 chunks per batch; CPB | 1024
    const int m0     = (wave % MSPLIT) * MW * 16;
    const int nb     = (wave / MSPLIT) * NW * 16;

    // A fragments: [o][k] bf16, k-contiguous -> direct 16B loads
    bf16x8 af[MW][KT];
    {
        const unsigned short* Ab = A + (size_t)b * aBStride;
#pragma unroll
        for (int mw = 0; mw < MW; ++mw)
#pragma unroll
            for (int kt = 0; kt < KT; ++kt)
                af[mw][kt] = *(const bf16x8*)(Ab + (size_t)(m0 + mw * 16 + r) * K + kt * 32 + q * 8);
    }

    f4  va[ITERS], vb[ITERS];
    us4 ua[ITERS], ub[ITERS];

    auto issue_loads = [&](int chunk) {
        const long base = (long)(chunk & 1023) * 64 + m4;
        if constexpr (SRCBF) {
            const unsigned short* sp = (const unsigned short*)srcv + (size_t)b * srcBStride + base;
#pragma unroll
            for (int i = 0; i < ITERS; ++i) {
                const int kp = i * 16 + h;
                ua[i] = *(const us4*)(sp + (size_t)(2 * kp) * NPIX);
                ub[i] = *(const us4*)(sp + (size_t)(2 * kp + 1) * NPIX);
            }
        } else {
            const float* sp = (const float*)srcv + (size_t)b * srcBStride + base;
#pragma unroll
            for (int i = 0; i < ITERS; ++i) {
                const int kp = i * 16 + h;
                va[i] = *(const f4*)(sp + (size_t)(2 * kp) * NPIX);
                vb[i] = *(const f4*)(sp + (size_t)(2 * kp + 1) * NPIX);
            }
        }
    };

    auto write_lds = [&](unsigned* B) {
#pragma unroll
        for (int i = 0; i < ITERS; ++i) {
            const int kp = i * 16 + h;
#pragma unroll
            for (int j = 0; j < 4; ++j) {
                const int n = m4 + j;
                unsigned val;
                if constexpr (SRCBF)
                    val = (unsigned)ua[i][j] | ((unsigned)ub[i][j] << 16);
                else
                    val = (unsigned)f2bf(va[i][j]) | ((unsigned)f2bf(vb[i][j]) << 16);
                B[n * KW + ((((kp >> 2) ^ ((n >> 1) & 7)) << 2) | (kp & 3))] = val;
            }
        }
    };

    auto compute_chunk = [&](const unsigned* B, int n0c) {
        f32x4 acc[MW][NW];
#pragma unroll
        for (int mw = 0; mw < MW; ++mw)
#pragma unroll
            for (int nw = 0; nw < NW; ++nw) acc[mw][nw] = (f32x4){0.f, 0.f, 0.f, 0.f};

#pragma unroll
        for (int kt = 0; kt < KT; ++kt) {
            bf16x8 bf[NW];
#pragma unroll
            for (int nw = 0; nw < NW; ++nw) {
                const int n = nb + nw * 16 + r;
                bf[nw] = *(const bf16x8*)(&B[n * KW + (((kt * 4 + q) ^ ((n >> 1) & 7)) << 2)]);
            }
#pragma unroll
            for (int mw = 0; mw < MW; ++mw)
#pragma unroll
                for (int nw = 0; nw < NW; ++nw)
                    acc[mw][nw] = __builtin_amdgcn_mfma_f32_16x16x32_bf16(
                        af[mw][kt], bf[nw], acc[mw][nw], 0, 0, 0);
        }

        // store: C/D layout col=lane&15 (pixel), row=(lane>>4)*4+reg (channel)
#pragma unroll
        for (int mw = 0; mw < MW; ++mw) {
            const int obase = m0 + mw * 16 + q * 4;
#pragma unroll
            for (int nw = 0; nw < NW; ++nw) {
                const int n = n0c + nb + nw * 16 + r;
#pragma unroll
                for (int rr = 0; rr < 4; ++rr) {
                    const int o = obase + rr;
                    float* dst;
                    if (SPLIT && o >= 128)
                        dst = out2 + (size_t)b * out2BStride + (size_t)(o - 128) * NPIX + n;
                    else
                        dst = out + (size_t)b * outBStride + (size_t)o * NPIX + n;
                    *dst = acc[mw][nw][rr];
                }
            }
        }
    };

    // prologue
    issue_loads(chunk0);
    write_lds(&Blds[0][0]);
    __syncthreads();

#pragma unroll
    for (int c = 0; c < CPB; ++c) {
        if (c + 1 < CPB) {
            issue_loads(chunk0 + c + 1);
            __builtin_amdgcn_sched_barrier(0);
        }
        compute_chunk(&Blds[c & 1][0], ((chunk0 + c) & 1023) * 64);
        if (c + 1 < CPB) {
            // wait for loads(c+1) only; stores(c) remain in flight
            asm volatile("s_waitcnt vmcnt(%0)" :: "n"(SCNT) : "memory");
            __builtin_amdgcn_sched_barrier(0);
            write_lds(&Blds[(c + 1) & 1][0]);
            asm volatile("s_waitcnt lgkmcnt(0)" ::: "memory");
            __builtin_amdgcn_sched_barrier(0);
            __builtin_amdgcn_s_barrier();
            __builtin_amdgcn_sched_barrier(0);
        }
    }
}

// ---------------- pyramid depthwise conv (reflect pad, dilation=group) ------
// One (plane, 32-row tile) per block. fp32 in, bf16 out (paired-col u32 stores).
__device__ __forceinline__ int refl(int p) {
    return (p < 0) ? -p : ((p > 255) ? 510 - p : p);
}

__global__ __launch_bounds__(256) void pyramid_k(
    const float* __restrict__ kvraw, const float* __restrict__ qhraw,
    const float* __restrict__ qlraw,
    unsigned short* __restrict__ kvp, unsigned short* __restrict__ qhp,
    unsigned short* __restrict__ qlp,
    const float* __restrict__ kv1, const float* __restrict__ kv2, const float* __restrict__ kv3,
    const float* __restrict__ qh1, const float* __restrict__ qh2, const float* __restrict__ qh3,
    const float* __restrict__ ql1, const float* __restrict__ ql2, const float* __restrict__ ql3) {
    const int t  = threadIdx.x;
    const int bi = blockIdx.x;
    const int yt = bi & 7, pl = bi >> 3;
    const int y0 = yt * 32;

    const float* in; unsigned short* outp; int C, c;
    const float *w1, *w2, *w3;
    if (pl < 256)      { in = kvraw + (size_t)pl * NPIX; outp = kvp + (size_t)pl * NPIX;
                         C = 128; c = pl & 127; w1 = kv1; w2 = kv2; w3 = kv3; }
    else if (pl < 320) { const int p2 = pl - 256; in = qhraw + (size_t)p2 * NPIX; outp = qhp + (size_t)p2 * NPIX;
                         C = 32; c = p2 & 31; w1 = qh1; w2 = qh2; w3 = qh3; }
    else               { const int p2 = pl - 320; in = qlraw + (size_t)p2 * NPIX; outp = qlp + (size_t)p2 * NPIX;
                         C = 16; c = p2 & 15; w1 = ql1; w2 = ql2; w3 = ql3; }
    const int G = C >> 2;
    const int g = (c >= 3 * G) ? 3 : (c >= 2 * G) ? 2 : (c >= G) ? 1 : 0;

    const int half = t >> 7, c2 = (t & 127) * 2;
    unsigned* outw = (unsigned*)outp;

    if (g == 0) {  // passthrough + bf16 cast
#pragma unroll
        for (int i = 0; i < 16; ++i) {
            const int y = y0 + half * 16 + i;
            const float2 v = *(const float2*)(in + (size_t)y * 256 + c2);
            outw[y * 128 + (t & 127)] = (unsigned)f2bf(v.x) | ((unsigned)f2bf(v.y) << 16);
        }
        return;
    }

    __shared__ float rows[38][256];
    for (int idx = t; idx < 38 * 64; idx += 256) {
        const int rr2 = idx >> 6, qd = idx & 63;
        const int yy = refl(y0 - 3 + rr2);
        *(f4*)(&rows[rr2][qd * 4]) = *(const f4*)(in + (size_t)yy * 256 + qd * 4);
    }
    __syncthreads();

    const float* wp = (g == 1 ? w1 : (g == 2 ? w2 : w3)) + (c - g * G) * 9;
    float w[9];
#pragma unroll
    for (int i = 0; i < 9; ++i) w[i] = wp[i];

    const int xm0 = refl(c2 - g), xp0 = refl(c2 + g);
    const int xm1 = refl(c2 + 1 - g), xp1 = refl(c2 + 1 + g);

#pragma unroll
    for (int i = 0; i < 16; ++i) {
        const int ro = half * 16 + i;
        float s0 = 0.f, s1 = 0.f;
#pragma unroll
        for (int ky = 0; ky < 3; ++ky) {
            const float* rp = rows[ro + 3 + (ky - 1) * g];
            s0 = fmaf(w[ky * 3 + 0], rp[xm0], s0);
            s0 = fmaf(w[ky * 3 + 1], rp[c2], s0);
            s0 = fmaf(w[ky * 3 + 2], rp[xp0], s0);
            s1 = fmaf(w[ky * 3 + 0], rp[xm1], s1);
            s1 = fmaf(w[ky * 3 + 1], rp[c2 + 1], s1);
            s1 = fmaf(w[ky * 3 + 2], rp[xp1], s1);
        }
        outw[(y0 + ro) * 128 + (t & 127)] = (unsigned)f2bf(s0) | ((unsigned)f2bf(s1) << 16);
    }
}

// ---------------- MFMA scores + squared-norm partials (per slice) ----------
// part[((b*4+hd)*64 + slice)*224 + idx]: idx<192 = S[c][d]; 192..207 kk[d];
// 208..219 qq[c].  No atomics; finalize reduces the 64 slices.
__global__ __launch_bounds__(256) void scores_k(const unsigned short* __restrict__ qhp,
                                                const unsigned short* __restrict__ qlp,
                                                const unsigned short* __restrict__ kvp,
                                                float* __restrict__ part) {
    const int t = threadIdx.x;
    const int wave = t >> 6, lane = t & 63;
    const int r = lane & 15, q = lane >> 4;
    const int slice = blockIdx.x;   // 64 slices of 1024 px
    const int hd = blockIdx.y;
    const int b = blockIdx.z;

    const unsigned short* qrow;
    if (r < 8)       qrow = qhp + (size_t)(b * 32 + hd * 8 + r) * NPIX;
    else if (r < 12) qrow = qlp + (size_t)(b * 16 + hd * 4 + (r - 8)) * NPIX;
    else             qrow = qhp + (size_t)(b * 32 + hd * 8) * NPIX;  // dummy
    const unsigned short* krow = kvp + (size_t)(b * 128 + hd * 16 + r) * NPIX;

    const int base = slice * 1024 + wave * 256;
    f32x4 acc = (f32x4){0.f, 0.f, 0.f, 0.f};
    float qq = 0.f, kk = 0.f;
#pragma unroll
    for (int c8 = 0; c8 < 8; ++c8) {
        const int n = base + c8 * 32 + q * 8;
        const bf16x8 a  = *(const bf16x8*)(qrow + n);
        const bf16x8 bb = *(const bf16x8*)(krow + n);
        acc = __builtin_amdgcn_mfma_f32_16x16x32_bf16(a, bb, acc, 0, 0, 0);
#pragma unroll
        for (int j = 0; j < 8; ++j) {
            const float av = bf2f((unsigned short)a[j]);
            const float bv = bf2f((unsigned short)bb[j]);
            qq = fmaf(av, av, qq);
            kk = fmaf(bv, bv, kk);
        }
    }
    qq += __shfl_xor(qq, 16); qq += __shfl_xor(qq, 32);
    kk += __shfl_xor(kk, 16); kk += __shfl_xor(kk, 32);

    __shared__ float Sred[4][16][16];
    __shared__ float qred[4][16];
    __shared__ float kred[4][16];
#pragma unroll
    for (int rr = 0; rr < 4; ++rr) Sred[wave][q * 4 + rr][r] = acc[rr];
    if (q == 0) { qred[wave][r] = qq; kred[wave][r] = kk; }
    __syncthreads();

    float* pb = part + ((size_t)((b * 4 + hd) * 64 + slice)) * 224;
    if (t < 192) {
        const int c = t >> 4, d = t & 15;
        pb[t] = Sred[0][c][d] + Sred[1][c][d] + Sred[2][c][d] + Sred[3][c][d];
    } else if (t < 208) {
        const int d = t - 192;
        pb[t] = kred[0][d] + kred[1][d] + kred[2][d] + kred[3][d];
    } else if (t < 220) {
        const int c = t - 208;
        pb[t] = qred[0][c] + qred[1][c] + qred[2][c] + qred[3][c];
    }
}

// ---------------- softmax + fold output projections into CT (bf16) ---------
__global__ __launch_bounds__(256) void finalize_k(const float* __restrict__ part,
                                                  const float* __restrict__ w_ph,
                                                  const float* __restrict__ w_pl,
                                                  const float* __restrict__ temp,
                                                  unsigned short* __restrict__ CT) {
    __shared__ float As[192];
    __shared__ float kks[16];
    __shared__ float qqs[12];
    const int t = threadIdx.x;
    const int hd = blockIdx.x;
    const int b = blockIdx.y;

    const float* pb = part + ((size_t)(b * 4 + hd) * 64) * 224;
    float acc = 0.f;
    if (t < 220)
        for (int s2 = 0; s2 < 64; ++s2) acc += pb[s2 * 224 + t];
    if (t >= 192 && t < 208) kks[t - 192] = acc;
    else if (t >= 208 && t < 220) qqs[t - 208] = acc;
    __syncthreads();

    if (t < 192) {
        const int c = t >> 4, d = t & 15;
        const float invk = 1.f / fmaxf(sqrtf(kks[d]), 1e-12f);
        const float invq = 1.f / fmaxf(sqrtf(qqs[c]), 1e-12f);
        float s = acc * invq * invk * temp[hd];
        float m = s;
        for (int mask = 8; mask >= 1; mask >>= 1) m = fmaxf(m, __shfl_xor(m, mask, 16));
        const float e = expf(s - m);
        float sum = e;
        for (int mask = 8; mask >= 1; mask >>= 1) sum += __shfl_xor(sum, mask, 16);
        As[c * 16 + d] = e / sum;
    }
    __syncthreads();

    unsigned short* CTb = CT + (size_t)b * 192 * 64;
    for (int idx = t; idx < 3072; idx += 256) {
        const int d = idx & 15, rr = idx >> 4;
        float s = 0.f;
        if (rr < 128) {
#pragma unroll
            for (int c = 0; c < 8; ++c)
                s = fmaf(w_ph[rr * 32 + hd * 8 + c], As[c * 16 + d], s);
        } else {
            const int r2 = rr - 128;
#pragma unroll
            for (int c = 0; c < 4; ++c)
                s = fmaf(w_pl[r2 * 16 + hd * 4 + c], As[(8 + c) * 16 + d], s);
        }
        CTb[(size_t)rr * 64 + hd * 16 + d] = f2bf(s);
    }
}

// ---------------------------------------------------------------------------
extern "C" void kernel_launch(void* const* d_in, const int* in_sizes, int n_in,
                              void* d_out, int out_size, void* d_ws, size_t ws_size,
                              hipStream_t stream) {
    const float* x      = (const float*)d_in[0];
    const float* x_h    = (const float*)d_in[1];
    const float* x_l    = (const float*)d_in[2];
    const float* w_kv   = (const float*)d_in[3];
    const float* kv_dw1 = (const float*)d_in[4];
    const float* kv_dw2 = (const float*)d_in[5];
    const float* kv_dw3 = (const float*)d_in[6];
    const float* w_qh   = (const float*)d_in[7];
    const float* qh_dw1 = (const float*)d_in[8];
    const float* qh_dw2 = (const float*)d_in[9];
    const float* qh_dw3 = (const float*)d_in[10];
    const float* w_ql   = (const float*)d_in[11];
    const float* ql_dw1 = (const float*)d_in[12];
    const float* ql_dw2 = (const float*)d_in[13];
    const float* ql_dw3 = (const float*)d_in[14];
    const float* w_ph   = (const float*)d_in[15];
    const float* w_pl   = (const float*)d_in[16];
    const float* temp   = (const float*)d_in[17];
    float* out = (float*)d_out;

    char* ws = (char*)d_ws;
    float*          part  = (float*)(ws + 0);                   // 458752 B
    unsigned short* wkv_b = (unsigned short*)(ws + 458752);     // 65536 B
    unsigned short* wqh_b = (unsigned short*)(ws + 524288);     // 8192 B
    unsigned short* wql_b = (unsigned short*)(ws + 532480);     // 2048 B
    unsigned short* CT    = (unsigned short*)(ws + 540672);     // 49152 B
    float*          kvraw = (float*)(ws + 589824);              // 67108864 B
    float*          qhraw = (float*)(ws + 67698688);            // 16777216 B
    float*          qlraw = (float*)(ws + 84475904);            //  8388608 B
    unsigned short* kvpyr = (unsigned short*)(ws + 92864512);   // 33554432 B
    unsigned short* qhpyr = (unsigned short*)(ws + 126418944);  //  8388608 B
    unsigned short* qlpyr = (unsigned short*)(ws + 134807552);  //  4194304 B

    cast_w_k<<<148, 256, 0, stream>>>(w_kv, w_qh, w_ql, wkv_b, wqh_b, wql_b);

    // kv: O=128 (MW=2,MS=4), K=256 (KT=8), CPB=4
    gemm_mfma_k<2, 4, 8, 4, false, false><<<512, 256, 0, stream>>>(
        x, wkv_b, kvraw, nullptr, 256L * NPIX, 0L, 128L * NPIX, 0L);
    // qh: O=32 (MW=2,MS=1), K=128 (KT=4)
    gemm_mfma_k<2, 1, 4, 4, false, false><<<512, 256, 0, stream>>>(
        x_h, wqh_b, qhraw, nullptr, 128L * NPIX, 0L, 32L * NPIX, 0L);
    // ql: O=16 (MW=1,MS=1), K=64 (KT=2)
    gemm_mfma_k<1, 1, 2, 4, false, false><<<512, 256, 0, stream>>>(
        x_l, wql_b, qlraw, nullptr, 64L * NPIX, 0L, 16L * NPIX, 0L);

    // merged pyramid: 352 planes x 8 y-tiles
    pyramid_k<<<2816, 256, 0, stream>>>(kvraw, qhraw, qlraw, kvpyr, qhpyr, qlpyr,
                                        kv_dw1, kv_dw2, kv_dw3,
                                        qh_dw1, qh_dw2, qh_dw3,
                                        ql_dw1, ql_dw2, ql_dw3);

    scores_k<<<dim3(64, 4, 2), 256, 0, stream>>>(qhpyr, qlpyr, kvpyr, part);
    finalize_k<<<dim3(4, 2), 256, 0, stream>>>(part, w_ph, w_pl, temp, CT);

    // output GEMM: O=192 (MW=3,MS=4), K=64 (KT=2); A = CT per batch;
    // B = v = kvpyr channels 64..127 (bf16); rows >=128 go to out_l.
    gemm_mfma_k<3, 4, 2, 4, true, true><<<512, 256, 0, stream>>>(
        (const void*)(kvpyr + 64L * NPIX), CT, out, out + 2L * 128 * NPIX,
        128L * NPIX, 192L * 64, 128L * NPIX, 64L * NPIX);
}